// Round 5
// baseline (239.737 us; speedup 1.0000x reference)
//
#include <hip/hip_runtime.h>
#include <hip/hip_bf16.h>
#include <stdint.h>

// CortexBlock — reference collapses (U,V start at 0; update is multiplicative
// in the state, so the fast-weight path is identically 0):
//   y[row,h,:] = sigmoid((q_h.k_h)/8) * v_h ;  out = y @ Wo^T
// Round 5: fp32->bf16 casts fused into GEMM register staging (cast_kernel
// removed). Wq/Wk rows interleaved at 16-col granularity via an in-kernel
// row remap so each wave fragment holds matching (q_d,k_d) pairs; score
// computed in the GEMM epilogue, only S [8192x16] + Vb leave the kernel.
#define D_MODEL 1024
#define N_HEADS 16
#define D_HEAD  64
#define SEQ_T   2048
#define BATCH   4

typedef unsigned short u16;
typedef __bf16 bf16x8 __attribute__((ext_vector_type(8)));
typedef float  f32x4  __attribute__((ext_vector_type(4)));

// ---- helpers ---------------------------------------------------------------
__device__ __forceinline__ u16 f2bf(float x) {  // RNE f32->bf16
  unsigned u = __float_as_uint(x);
  u += 0x7fffu + ((u >> 16) & 1u);
  return (u16)(u >> 16);
}
__device__ __forceinline__ unsigned pk2(float a, float b) {
  return (unsigned)f2bf(a) | ((unsigned)f2bf(b) << 16);
}
__device__ __forceinline__ uint4 cvt8(float4 lo, float4 hi) {  // 8 f32 -> 8 bf16
  uint4 o;
  o.x = pk2(lo.x, lo.y); o.y = pk2(lo.z, lo.w);
  o.z = pk2(hi.x, hi.y); o.w = pk2(hi.z, hi.w);
  return o;
}
__device__ __forceinline__ unsigned scale2(unsigned p, float s) {
  float lo = __uint_as_float(p << 16) * s;
  float hi = __uint_as_float(p & 0xffff0000u) * s;
  return pk2(lo, hi);
}
// virtual weight-row remap: rows [0,2048) = qk-interleaved (16-col blocks of
// Wq/Wk alternate within each head), rows [2048,3072) = Wv.
__device__ __forceinline__ const float* map_w_row(const float* wq, const float* wk,
                                                  const float* wv, int R) {
  if (R < 2048) {
    int h = R >> 7, c = R & 127, jj = c >> 4, l = c & 15;
    const float* s = (jj & 1) ? wk : wq;
    return s + (size_t)(h * 64 + (jj >> 1) * 16 + l) * D_MODEL;
  }
  return wv + (size_t)(R - 2048) * D_MODEL;
}

// ---- QKV GEMM with fused cast + score --------------------------------------
// C[M, 3072-virtual] = X[M,1024](fp32) * W[.,1024]^T(fp32, remapped rows).
// 128x128 tile, 4 waves (2x2 of 64x64), BK=32, mfma_f32_16x16x32_bf16.
// Register staging (fp32 global -> pk2 -> LDS bf16) + XOR chunk swizzle
// (chunk ^= (row>>1)&3) -> conflict-free ds_write_b128/ds_read_b128.
// bn<16: head-tile -> score epilogue (writes only S). bn>=16: v-tile -> Vb.
__global__ __launch_bounds__(256) void gemm_qkv_kernel(const float* __restrict__ X,
                                                       const float* __restrict__ Wq,
                                                       const float* __restrict__ Wk,
                                                       const float* __restrict__ Wv,
                                                       u16* __restrict__ Vb,
                                                       float* __restrict__ S) {
  constexpr int K = D_MODEL;
  __shared__ u16 As[128 * 32];
  __shared__ u16 Bs[128 * 32];
  const int tid  = threadIdx.x;
  const int lane = tid & 63;
  const int wave = tid >> 6;
  const int wm = (wave >> 1) * 64;
  const int wn = (wave & 1) * 64;
  const int bm = blockIdx.y * 128;
  const int bn = blockIdx.x;
  const int quad = lane >> 4;
  const int l16  = lane & 15;
  const int rchunk = quad ^ ((l16 >> 1) & 3);  // fragment read chunk

  // staging: thread -> rows lr, lr+64; 8-float chunk lch; swizzled LDS chunk
  const int lr = tid >> 2;
  const int lch = tid & 3;
  const int wch = lch ^ ((lr >> 1) & 3);
  const float4* Ap0 = (const float4*)(X + (size_t)(bm + lr) * K) + lch * 2;
  const float4* Ap1 = Ap0 + (size_t)16 * K;  // +64 rows (in float4 units: 64*256)
  const float4* Bp0 = (const float4*)map_w_row(Wq, Wk, Wv, bn * 128 + lr) + lch * 2;
  const float4* Bp1 = (const float4*)map_w_row(Wq, Wk, Wv, bn * 128 + lr + 64) + lch * 2;
  u16* Aw0 = As + lr * 32 + wch * 8;
  u16* Aw1 = Aw0 + 64 * 32;
  u16* Bw0 = Bs + lr * 32 + wch * 8;
  u16* Bw1 = Bw0 + 64 * 32;

  f32x4 acc[4][4];
  #pragma unroll
  for (int i = 0; i < 4; ++i)
    #pragma unroll
    for (int j = 0; j < 4; ++j) acc[i][j] = (f32x4){0.f, 0.f, 0.f, 0.f};

  float4 a0l = Ap0[0], a0h = Ap0[1];
  float4 a1l = Ap1[0], a1h = Ap1[1];
  float4 b0l = Bp0[0], b0h = Bp0[1];
  float4 b1l = Bp1[0], b1h = Bp1[1];

  for (int k0 = 0; k0 < K; k0 += 32) {
    __syncthreads();
    *(uint4*)Aw0 = cvt8(a0l, a0h);
    *(uint4*)Aw1 = cvt8(a1l, a1h);
    *(uint4*)Bw0 = cvt8(b0l, b0h);
    *(uint4*)Bw1 = cvt8(b1l, b1h);
    __syncthreads();
    if (k0 + 32 < K) {  // prefetch next chunk; latency hidden by MFMAs
      int f = (k0 + 32) >> 2;
      a0l = Ap0[f]; a0h = Ap0[f + 1];
      a1l = Ap1[f]; a1h = Ap1[f + 1];
      b0l = Bp0[f]; b0h = Bp0[f + 1];
      b1l = Bp1[f]; b1h = Bp1[f + 1];
    }
    bf16x8 af[4], bfr[4];
    #pragma unroll
    for (int i = 0; i < 4; ++i)
      af[i] = *(const bf16x8*)(As + (wm + i * 16 + l16) * 32 + rchunk * 8);
    #pragma unroll
    for (int j = 0; j < 4; ++j)
      bfr[j] = *(const bf16x8*)(Bs + (wn + j * 16 + l16) * 32 + rchunk * 8);
    #pragma unroll
    for (int i = 0; i < 4; ++i)
      #pragma unroll
      for (int j = 0; j < 4; ++j)
        acc[i][j] = __builtin_amdgcn_mfma_f32_16x16x32_bf16(af[i], bfr[j], acc[i][j], 0, 0, 0);
  }

  if (bn < N_HEADS) {
    // score epilogue: cols jj*16+l <-> (jj odd ? k : q)[d=(jj>>1)*16+l].
    // acc[i][j] (j even) pairs with acc[i][j+1]: q_d * k_d, same lane/row.
    float part[4][4];
    #pragma unroll
    for (int i = 0; i < 4; ++i)
      #pragma unroll
      for (int e = 0; e < 4; ++e)
        part[i][e] = acc[i][0][e] * acc[i][1][e] + acc[i][2][e] * acc[i][3][e];
    #pragma unroll
    for (int m = 1; m <= 8; m <<= 1)
      #pragma unroll
      for (int i = 0; i < 4; ++i)
        #pragma unroll
        for (int e = 0; e < 4; ++e)
          part[i][e] += __shfl_xor(part[i][e], m);  // reduce over l16
    __syncthreads();
    float* Sp = (float*)As;  // [128][2]
    if (l16 == 0) {
      #pragma unroll
      for (int i = 0; i < 4; ++i)
        #pragma unroll
        for (int e = 0; e < 4; ++e)
          Sp[(wm + i * 16 + quad * 4 + e) * 2 + (wave & 1)] = part[i][e];
    }
    __syncthreads();
    if (tid < 128) {
      float s = (Sp[tid * 2] + Sp[tid * 2 + 1]) * 0.125f;  // 1/sqrt(64)
      S[(size_t)(bm + tid) * N_HEADS + bn] = 1.f / (1.f + __expf(-s));
    }
  } else {
    const int cb = (bn - N_HEADS) * 128;
    #pragma unroll
    for (int i = 0; i < 4; ++i)
      #pragma unroll
      for (int j = 0; j < 4; ++j)
        #pragma unroll
        for (int e = 0; e < 4; ++e) {
          int row = bm + wm + i * 16 + quad * 4 + e;
          int col = cb + wn + j * 16 + l16;
          Vb[(size_t)row * D_MODEL + col] = f2bf(acc[i][j][e]);
        }
  }
}

// ---- out GEMM: out[M,1024] = (S(row,head)*V)[M,1024] * Wo[1024,1024]^T -----
// A = Vb bf16 (scale fused during staging); B = Wo fp32 (cast fused).
__global__ __launch_bounds__(256) void gemm_out_kernel(const u16* __restrict__ A,
                                                       const float* __restrict__ Wo,
                                                       const float* __restrict__ S,
                                                       float* __restrict__ C) {
  constexpr int K = D_MODEL, N = D_MODEL;
  __shared__ u16 As[128 * 32];
  __shared__ u16 Bs[128 * 32];
  const int tid  = threadIdx.x;
  const int lane = tid & 63;
  const int wave = tid >> 6;
  const int wm = (wave >> 1) * 64;
  const int wn = (wave & 1) * 64;
  const int bm = blockIdx.y * 128;
  const int bn = blockIdx.x * 128;
  const int quad = lane >> 4;
  const int l16  = lane & 15;
  const int rchunk = quad ^ ((l16 >> 1) & 3);

  const int lr = tid >> 2;
  const int lch = tid & 3;
  const int wch = lch ^ ((lr >> 1) & 3);
  const u16* Ap0 = A + (size_t)(bm + lr) * K + lch * 8;
  const u16* Ap1 = Ap0 + (size_t)64 * K;
  const float4* Bp0 = (const float4*)(Wo + (size_t)(bn + lr) * K) + lch * 2;
  const float4* Bp1 = Bp0 + (size_t)16 * K;  // +64 rows in float4 units
  u16* Aw0 = As + lr * 32 + wch * 8;
  u16* Aw1 = Aw0 + 64 * 32;
  u16* Bw0 = Bs + lr * 32 + wch * 8;
  u16* Bw1 = Bw0 + 64 * 32;
  const float* Sp0 = S + (size_t)(bm + lr) * N_HEADS;
  const float* Sp1 = Sp0 + (size_t)64 * N_HEADS;

  f32x4 acc[4][4];
  #pragma unroll
  for (int i = 0; i < 4; ++i)
    #pragma unroll
    for (int j = 0; j < 4; ++j) acc[i][j] = (f32x4){0.f, 0.f, 0.f, 0.f};

  uint4 a0 = *(const uint4*)Ap0;
  uint4 a1 = *(const uint4*)Ap1;
  float4 b0l = Bp0[0], b0h = Bp0[1];
  float4 b1l = Bp1[0], b1h = Bp1[1];
  float rs0 = Sp0[0], rs1 = Sp1[0];

  for (int k0 = 0; k0 < K; k0 += 32) {
    __syncthreads();
    uint4 w0, w1;
    w0.x = scale2(a0.x, rs0); w0.y = scale2(a0.y, rs0);
    w0.z = scale2(a0.z, rs0); w0.w = scale2(a0.w, rs0);
    w1.x = scale2(a1.x, rs1); w1.y = scale2(a1.y, rs1);
    w1.z = scale2(a1.z, rs1); w1.w = scale2(a1.w, rs1);
    *(uint4*)Aw0 = w0;
    *(uint4*)Aw1 = w1;
    *(uint4*)Bw0 = cvt8(b0l, b0h);
    *(uint4*)Bw1 = cvt8(b1l, b1h);
    __syncthreads();
    if (k0 + 32 < K) {
      a0 = *(const uint4*)(Ap0 + k0 + 32);
      a1 = *(const uint4*)(Ap1 + k0 + 32);
      int f = (k0 + 32) >> 2;
      b0l = Bp0[f]; b0h = Bp0[f + 1];
      b1l = Bp1[f]; b1h = Bp1[f + 1];
      rs0 = Sp0[(k0 + 32) >> 6];  // head = k/64 (BK=32 stays within one head)
      rs1 = Sp1[(k0 + 32) >> 6];
    }
    bf16x8 af[4], bfr[4];
    #pragma unroll
    for (int i = 0; i < 4; ++i)
      af[i] = *(const bf16x8*)(As + (wm + i * 16 + l16) * 32 + rchunk * 8);
    #pragma unroll
    for (int j = 0; j < 4; ++j)
      bfr[j] = *(const bf16x8*)(Bs + (wn + j * 16 + l16) * 32 + rchunk * 8);
    #pragma unroll
    for (int i = 0; i < 4; ++i)
      #pragma unroll
      for (int j = 0; j < 4; ++j)
        acc[i][j] = __builtin_amdgcn_mfma_f32_16x16x32_bf16(af[i], bfr[j], acc[i][j], 0, 0, 0);
  }

  #pragma unroll
  for (int i = 0; i < 4; ++i)
    #pragma unroll
    for (int j = 0; j < 4; ++j)
      #pragma unroll
      for (int e = 0; e < 4; ++e) {
        int row = bm + wm + i * 16 + quad * 4 + e;
        int col = bn + wn + j * 16 + l16;
        C[(size_t)row * N + col] = acc[i][j][e];
      }
}

// ---- launch ----------------------------------------------------------------
extern "C" void kernel_launch(void* const* d_in, const int* in_sizes, int n_in,
                              void* d_out, int out_size, void* d_ws, size_t ws_size,
                              hipStream_t stream) {
  const float* hs = (const float*)d_in[0];
  const float* Wq = (const float*)d_in[3];
  const float* Wk = (const float*)d_in[4];
  const float* Wv = (const float*)d_in[5];
  const float* Wo = (const float*)d_in[6];
  // d_in[1,2,7,8,9] dead (fast-weight state identically zero).

  char* ws = (char*)d_ws;
  u16*  Vb = (u16*)ws;                     // [8192][1024] bf16 (16 MB)
  float* Sb = (float*)(ws + (16u << 20));  // [8192][16] f32 (512 KB)
  float* out = (float*)d_out;

  gemm_qkv_kernel<<<dim3(24, 64), 256, 0, stream>>>(hs, Wq, Wk, Wv, Vb, Sb);
  gemm_out_kernel<<<dim3(8, 64), 256, 0, stream>>>(Vb, Wo, Sb, out);
}

// Round 6
// 214.420 us; speedup vs baseline: 1.1181x; 1.1181x over previous
//
#include <hip/hip_runtime.h>
#include <hip/hip_bf16.h>
#include <stdint.h>

// CortexBlock — reference collapses (U,V start at 0; update is multiplicative
// in the state, so the fast-weight path is identically 0):
//   y[row,h,:] = sigmoid((q_h.k_h)/8) * v_h ;  out = y @ Wo^T
// Round 6: back to r4 pipeline (pre-cast bf16 operands — r5 showed fp32
// staging doubles the HBM stream); GEMM K-loops restructured to LDS
// double-buffering (1 barrier/tile, prefetch consumed a full iter later).
#define D_MODEL 1024
#define N_HEADS 16
#define D_HEAD  64
#define SEQ_T   2048
#define BATCH   4

typedef unsigned short u16;
typedef __bf16 bf16x8 __attribute__((ext_vector_type(8)));
typedef float  f32x4  __attribute__((ext_vector_type(4)));

#define NT 32          // K tiles (K=1024, BK=32)
#define BUF 4096       // u16 elements per LDS buffer (128*32)

// ---- helpers ---------------------------------------------------------------
__device__ __forceinline__ u16 f2bf(float x) {  // RNE f32->bf16
  unsigned u = __float_as_uint(x);
  u += 0x7fffu + ((u >> 16) & 1u);
  return (u16)(u >> 16);
}
__device__ __forceinline__ unsigned pk2(float a, float b) {
  return (unsigned)f2bf(a) | ((unsigned)f2bf(b) << 16);
}
__device__ __forceinline__ unsigned scale2(unsigned p, float s) {
  float lo = __uint_as_float(p << 16) * s;
  float hi = __uint_as_float(p & 0xffff0000u) * s;
  return pk2(lo, hi);
}

// ---- fused cast fp32 -> bf16 with weight-row remap -------------------------
// Wb rows: [0,2048): qk-interleaved: row h*128 + jj*16 + l  (jj=0..7) =
//   (jj odd ? Wk : Wq)[h*64 + (jj>>1)*16 + l];  [2048,3072): Wv; [3072,4096): Wo.
__global__ __launch_bounds__(256) void cast_kernel(const float* __restrict__ hs,
                                                   const float* __restrict__ wq,
                                                   const float* __restrict__ wk,
                                                   const float* __restrict__ wv,
                                                   const float* __restrict__ wo,
                                                   u16* __restrict__ Xb,
                                                   u16* __restrict__ Wb) {
  int i = blockIdx.x * 256 + threadIdx.x;  // float4 units
  const float* src; u16* dst; int soff, doff;
  if (i < (2 << 20)) {                     // X: 2M float4
    src = hs; dst = Xb; soff = i; doff = i;
  } else {
    int j = i - (2 << 20);                 // W: 1M float4
    int R = j >> 8;                        // dest row (block-uniform)
    int col4 = j & 255;
    int srow;
    if (R < 2048) {
      int h = R >> 7, c = R & 127, jj = c >> 4, l = c & 15;
      srow = h * 64 + (jj >> 1) * 16 + l;
      src = (jj & 1) ? wk : wq;
    } else if (R < 3072) { src = wv; srow = R - 2048; }
    else                 { src = wo; srow = R - 3072; }
    dst = Wb; soff = srow * 256 + col4; doff = R * 256 + col4;
  }
  float4 v = ((const float4*)src)[soff];
  uint2 o; o.x = pk2(v.x, v.y); o.y = pk2(v.z, v.w);
  ((uint2*)dst)[doff] = o;
}

// ---- QKV GEMM with fused score ---------------------------------------------
// C[M, 3072-virtual] = X[M,1024] * Wb[qk|v][.,1024]^T, bf16 operands.
// 128x128 tile, 4 waves (2x2 of 64x64), BK=32, mfma_f32_16x16x32_bf16.
// LDS DOUBLE-BUFFERED (1 barrier/tile): compute buf p while staging tile t+1
// into buf p^1 from regs prefetched a full iteration earlier. XOR chunk
// swizzle (chunk ^= (row>>1)&3) keeps ds ops conflict-free (r4: 0 conflicts).
// bn<16: head-tile -> score epilogue (writes only S). bn>=16: v-tile -> Vb.
__global__ __launch_bounds__(256, 4) void gemm_qkv_kernel(const u16* __restrict__ A,
                                                          const u16* __restrict__ B,
                                                          u16* __restrict__ Vb,
                                                          float* __restrict__ S) {
  constexpr int K = D_MODEL;
  __shared__ u16 As[2 * BUF];
  __shared__ u16 Bs[2 * BUF];
  const int tid  = threadIdx.x;
  const int lane = tid & 63;
  const int wave = tid >> 6;
  const int wm = (wave >> 1) * 64;
  const int wn = (wave & 1) * 64;
  const int bm = blockIdx.y * 128;
  const int bn = blockIdx.x;
  const int quad = lane >> 4;
  const int l16  = lane & 15;
  const int rchunk = quad ^ ((l16 >> 1) & 3);  // fragment read chunk

  // staging: thread -> rows lr, lr+64; chunk tid&3; swizzled LDS chunk
  const int lr = tid >> 2;
  const int lch = tid & 3;
  const int wch = lch ^ ((lr >> 1) & 3);
  const u16* Ap0 = A + (size_t)(bm + lr) * K + lch * 8;
  const u16* Ap1 = Ap0 + (size_t)64 * K;
  const u16* Bp0 = B + (size_t)(bn * 128 + lr) * K + lch * 8;
  const u16* Bp1 = Bp0 + (size_t)64 * K;
  u16* Aw0 = As + lr * 32 + wch * 8;
  u16* Aw1 = Aw0 + 64 * 32;
  u16* Bw0 = Bs + lr * 32 + wch * 8;
  u16* Bw1 = Bw0 + 64 * 32;

  f32x4 acc[4][4];
  #pragma unroll
  for (int i = 0; i < 4; ++i)
    #pragma unroll
    for (int j = 0; j < 4; ++j) acc[i][j] = (f32x4){0.f, 0.f, 0.f, 0.f};

  // prologue: tile 0 -> buf0; regs <- tile 1
  uint4 a0 = *(const uint4*)Ap0;
  uint4 a1 = *(const uint4*)Ap1;
  uint4 b0 = *(const uint4*)Bp0;
  uint4 b1 = *(const uint4*)Bp1;
  *(uint4*)Aw0 = a0; *(uint4*)Aw1 = a1;
  *(uint4*)Bw0 = b0; *(uint4*)Bw1 = b1;
  a0 = *(const uint4*)(Ap0 + 32);
  a1 = *(const uint4*)(Ap1 + 32);
  b0 = *(const uint4*)(Bp0 + 32);
  b1 = *(const uint4*)(Bp1 + 32);
  __syncthreads();

  #pragma unroll 2
  for (int t = 0; t < NT; ++t) {
    const int p = t & 1;
    const u16* Ar = As + p * BUF;
    const u16* Br = Bs + p * BUF;
    bf16x8 af[4], bfr[4];
    #pragma unroll
    for (int i = 0; i < 4; ++i)
      af[i] = *(const bf16x8*)(Ar + (wm + i * 16 + l16) * 32 + rchunk * 8);
    #pragma unroll
    for (int j = 0; j < 4; ++j)
      bfr[j] = *(const bf16x8*)(Br + (wn + j * 16 + l16) * 32 + rchunk * 8);
    if (t + 1 < NT) {  // stage tile t+1 into other buffer
      const int q = (p ^ 1) * BUF;
      *(uint4*)(Aw0 + q) = a0; *(uint4*)(Aw1 + q) = a1;
      *(uint4*)(Bw0 + q) = b0; *(uint4*)(Bw1 + q) = b1;
      if (t + 2 < NT) {  // prefetch tile t+2 (consumed next iteration)
        const int o = (t + 2) * 32;
        a0 = *(const uint4*)(Ap0 + o);
        a1 = *(const uint4*)(Ap1 + o);
        b0 = *(const uint4*)(Bp0 + o);
        b1 = *(const uint4*)(Bp1 + o);
      }
    }
    #pragma unroll
    for (int i = 0; i < 4; ++i)
      #pragma unroll
      for (int j = 0; j < 4; ++j)
        acc[i][j] = __builtin_amdgcn_mfma_f32_16x16x32_bf16(af[i], bfr[j], acc[i][j], 0, 0, 0);
    __syncthreads();
  }

  if (bn < N_HEADS) {
    // score epilogue: cols jj*16+l <-> (jj odd ? k : q)[d=(jj>>1)*16+l].
    // acc[i][j] (j even) pairs with acc[i][j+1]: q_d * k_d, same lane/row.
    float part[4][4];
    #pragma unroll
    for (int i = 0; i < 4; ++i)
      #pragma unroll
      for (int e = 0; e < 4; ++e)
        part[i][e] = acc[i][0][e] * acc[i][1][e] + acc[i][2][e] * acc[i][3][e];
    #pragma unroll
    for (int m = 1; m <= 8; m <<= 1)
      #pragma unroll
      for (int i = 0; i < 4; ++i)
        #pragma unroll
        for (int e = 0; e < 4; ++e)
          part[i][e] += __shfl_xor(part[i][e], m);  // reduce over l16
    __syncthreads();
    float* Sp = (float*)As;  // [128][2]
    if (l16 == 0) {
      #pragma unroll
      for (int i = 0; i < 4; ++i)
        #pragma unroll
        for (int e = 0; e < 4; ++e)
          Sp[(wm + i * 16 + quad * 4 + e) * 2 + (wave & 1)] = part[i][e];
    }
    __syncthreads();
    if (tid < 128) {
      float s = (Sp[tid * 2] + Sp[tid * 2 + 1]) * 0.125f;  // 1/sqrt(64)
      S[(size_t)(bm + tid) * N_HEADS + bn] = 1.f / (1.f + __expf(-s));
    }
  } else {
    const int cb = (bn - N_HEADS) * 128;
    #pragma unroll
    for (int i = 0; i < 4; ++i)
      #pragma unroll
      for (int j = 0; j < 4; ++j)
        #pragma unroll
        for (int e = 0; e < 4; ++e) {
          int row = bm + wm + i * 16 + quad * 4 + e;
          int col = cb + wn + j * 16 + l16;
          Vb[(size_t)row * D_MODEL + col] = f2bf(acc[i][j][e]);
        }
  }
}

// ---- out GEMM: out[M,1024] = (S(row,head)*V)[M,1024] * Wo[1024,1024]^T -----
// A = Vb bf16 (scale fused at staging: head = tile>>1); B = Wb rows [3072,4096).
__global__ __launch_bounds__(256, 4) void gemm_out_kernel(const u16* __restrict__ A,
                                                          const u16* __restrict__ B,
                                                          const float* __restrict__ S,
                                                          float* __restrict__ C) {
  constexpr int K = D_MODEL, N = D_MODEL;
  __shared__ u16 As[2 * BUF];
  __shared__ u16 Bs[2 * BUF];
  const int tid  = threadIdx.x;
  const int lane = tid & 63;
  const int wave = tid >> 6;
  const int wm = (wave >> 1) * 64;
  const int wn = (wave & 1) * 64;
  const int bm = blockIdx.y * 128;
  const int bn = blockIdx.x * 128;
  const int quad = lane >> 4;
  const int l16  = lane & 15;
  const int rchunk = quad ^ ((l16 >> 1) & 3);

  const int lr = tid >> 2;
  const int lch = tid & 3;
  const int wch = lch ^ ((lr >> 1) & 3);
  const u16* Ap0 = A + (size_t)(bm + lr) * K + lch * 8;
  const u16* Ap1 = Ap0 + (size_t)64 * K;
  const u16* Bp0 = B + (size_t)(bn + lr) * K + lch * 8;
  const u16* Bp1 = Bp0 + (size_t)64 * K;
  u16* Aw0 = As + lr * 32 + wch * 8;
  u16* Aw1 = Aw0 + 64 * 32;
  u16* Bw0 = Bs + lr * 32 + wch * 8;
  u16* Bw1 = Bw0 + 64 * 32;
  const float* Sp0 = S + (size_t)(bm + lr) * N_HEADS;
  const float* Sp1 = Sp0 + (size_t)64 * N_HEADS;

  f32x4 acc[4][4];
  #pragma unroll
  for (int i = 0; i < 4; ++i)
    #pragma unroll
    for (int j = 0; j < 4; ++j) acc[i][j] = (f32x4){0.f, 0.f, 0.f, 0.f};

  // prologue: tile 0 (scaled) -> buf0; regs <- tile 1 (head(tile1)=0)
  uint4 a0 = *(const uint4*)Ap0;
  uint4 a1 = *(const uint4*)Ap1;
  uint4 b0 = *(const uint4*)Bp0;
  uint4 b1 = *(const uint4*)Bp1;
  float rs0 = Sp0[0], rs1 = Sp1[0];
  {
    uint4 w0, w1;
    w0.x = scale2(a0.x, rs0); w0.y = scale2(a0.y, rs0);
    w0.z = scale2(a0.z, rs0); w0.w = scale2(a0.w, rs0);
    w1.x = scale2(a1.x, rs1); w1.y = scale2(a1.y, rs1);
    w1.z = scale2(a1.z, rs1); w1.w = scale2(a1.w, rs1);
    *(uint4*)Aw0 = w0; *(uint4*)Aw1 = w1;
    *(uint4*)Bw0 = b0; *(uint4*)Bw1 = b1;
  }
  a0 = *(const uint4*)(Ap0 + 32);
  a1 = *(const uint4*)(Ap1 + 32);
  b0 = *(const uint4*)(Bp0 + 32);
  b1 = *(const uint4*)(Bp1 + 32);
  // rs for tile 1: head = 1>>1 = 0 (unchanged)
  __syncthreads();

  #pragma unroll 2
  for (int t = 0; t < NT; ++t) {
    const int p = t & 1;
    const u16* Ar = As + p * BUF;
    const u16* Br = Bs + p * BUF;
    bf16x8 af[4], bfr[4];
    #pragma unroll
    for (int i = 0; i < 4; ++i)
      af[i] = *(const bf16x8*)(Ar + (wm + i * 16 + l16) * 32 + rchunk * 8);
    #pragma unroll
    for (int j = 0; j < 4; ++j)
      bfr[j] = *(const bf16x8*)(Br + (wn + j * 16 + l16) * 32 + rchunk * 8);
    if (t + 1 < NT) {  // stage tile t+1 (scale by its head) into other buffer
      const int q = (p ^ 1) * BUF;
      uint4 w0, w1;
      w0.x = scale2(a0.x, rs0); w0.y = scale2(a0.y, rs0);
      w0.z = scale2(a0.z, rs0); w0.w = scale2(a0.w, rs0);
      w1.x = scale2(a1.x, rs1); w1.y = scale2(a1.y, rs1);
      w1.z = scale2(a1.z, rs1); w1.w = scale2(a1.w, rs1);
      *(uint4*)(Aw0 + q) = w0; *(uint4*)(Aw1 + q) = w1;
      *(uint4*)(Bw0 + q) = b0; *(uint4*)(Bw1 + q) = b1;
      if (t + 2 < NT) {  // prefetch tile t+2 + its scale
        const int o = (t + 2) * 32;
        a0 = *(const uint4*)(Ap0 + o);
        a1 = *(const uint4*)(Ap1 + o);
        b0 = *(const uint4*)(Bp0 + o);
        b1 = *(const uint4*)(Bp1 + o);
        rs0 = Sp0[(t + 2) >> 1];
        rs1 = Sp1[(t + 2) >> 1];
      }
    }
    #pragma unroll
    for (int i = 0; i < 4; ++i)
      #pragma unroll
      for (int j = 0; j < 4; ++j)
        acc[i][j] = __builtin_amdgcn_mfma_f32_16x16x32_bf16(af[i], bfr[j], acc[i][j], 0, 0, 0);
    __syncthreads();
  }

  #pragma unroll
  for (int i = 0; i < 4; ++i)
    #pragma unroll
    for (int j = 0; j < 4; ++j)
      #pragma unroll
      for (int e = 0; e < 4; ++e) {
        int row = bm + wm + i * 16 + quad * 4 + e;
        int col = bn + wn + j * 16 + l16;
        C[(size_t)row * N + col] = acc[i][j][e];
      }
}

// ---- launch ----------------------------------------------------------------
extern "C" void kernel_launch(void* const* d_in, const int* in_sizes, int n_in,
                              void* d_out, int out_size, void* d_ws, size_t ws_size,
                              hipStream_t stream) {
  const float* hs = (const float*)d_in[0];
  const float* Wq = (const float*)d_in[3];
  const float* Wk = (const float*)d_in[4];
  const float* Wv = (const float*)d_in[5];
  const float* Wo = (const float*)d_in[6];
  // d_in[1,2,7,8,9] dead (fast-weight state identically zero).

  char* ws = (char*)d_ws;
  u16*  Xb = (u16*)ws;                     // [8192][1024] bf16 (16 MB)
  u16*  Wb = (u16*)(ws + (16u << 20));     // [4096][1024] bf16 qk|v|o (8 MB)
  u16*  Vb = (u16*)(ws + (24u << 20));     // [8192][1024] bf16 (16 MB)
  float* Sb = (float*)(ws + (40u << 20));  // [8192][16] f32 (512 KB)
  float* out = (float*)d_out;

  cast_kernel<<<12288, 256, 0, stream>>>(hs, Wq, Wk, Wv, Wo, Xb, Wb);
  gemm_qkv_kernel<<<dim3(24, 64), 256, 0, stream>>>(Xb, Wb, Vb, Sb);
  gemm_out_kernel<<<dim3(8, 64), 256, 0, stream>>>(
      Vb, Wb + (size_t)3072 * D_MODEL, Sb, out);
}

// Round 7
// 205.832 us; speedup vs baseline: 1.1647x; 1.0417x over previous
//
#include <hip/hip_runtime.h>
#include <hip/hip_bf16.h>
#include <stdint.h>

// CortexBlock — reference collapses (U,V start at 0; update is multiplicative
// in the state, so the fast-weight path is identically 0):
//   y[row,h,:] = sigmoid((q_h.k_h)/8) * v_h ;  out = y @ Wo^T
// Round 7: gemm_qkv = LDS double-buffer + global_load_lds DMA staging
// (DMA for tile t+1 issued at top of iter t, drained at the end-of-iter
// barrier -> latency hidden behind 16 MFMAs; no ds_write staging traffic).
// gemm_out keeps reg staging on A (S-scale fused) + DMA on B.
#define D_MODEL 1024
#define N_HEADS 16
#define D_HEAD  64
#define SEQ_T   2048
#define BATCH   4

typedef unsigned short u16;
typedef __bf16 bf16x8 __attribute__((ext_vector_type(8)));
typedef float  f32x4  __attribute__((ext_vector_type(4)));

#define NT 32          // K tiles (K=1024, BK=32)
#define BUF 4096       // u16 elements per LDS buffer (128*32)

// ---- helpers ---------------------------------------------------------------
__device__ __forceinline__ u16 f2bf(float x) {  // RNE f32->bf16
  unsigned u = __float_as_uint(x);
  u += 0x7fffu + ((u >> 16) & 1u);
  return (u16)(u >> 16);
}
__device__ __forceinline__ unsigned pk2(float a, float b) {
  return (unsigned)f2bf(a) | ((unsigned)f2bf(b) << 16);
}
__device__ __forceinline__ unsigned scale2(unsigned p, float s) {
  float lo = __uint_as_float(p << 16) * s;
  float hi = __uint_as_float(p & 0xffff0000u) * s;
  return pk2(lo, hi);
}
// async global->LDS, 16B per lane; LDS dest must be wave-uniform base+lane*16.
__device__ __forceinline__ void cp16(const u16* g, u16* l) {
  __builtin_amdgcn_global_load_lds(
      (const __attribute__((address_space(1))) unsigned int*)g,
      (__attribute__((address_space(3))) unsigned int*)l, 16, 0, 0);
}

// ---- fused cast fp32 -> bf16 with weight-row remap -------------------------
// Wb rows: [0,2048): qk-interleaved: row h*128 + jj*16 + l  (jj=0..7) =
//   (jj odd ? Wk : Wq)[h*64 + (jj>>1)*16 + l];  [2048,3072): Wv; [3072,4096): Wo.
__global__ __launch_bounds__(256) void cast_kernel(const float* __restrict__ hs,
                                                   const float* __restrict__ wq,
                                                   const float* __restrict__ wk,
                                                   const float* __restrict__ wv,
                                                   const float* __restrict__ wo,
                                                   u16* __restrict__ Xb,
                                                   u16* __restrict__ Wb) {
  int i = blockIdx.x * 256 + threadIdx.x;  // float4 units
  const float* src; u16* dst; int soff, doff;
  if (i < (2 << 20)) {                     // X: 2M float4
    src = hs; dst = Xb; soff = i; doff = i;
  } else {
    int j = i - (2 << 20);                 // W: 1M float4
    int R = j >> 8;                        // dest row (block-uniform)
    int col4 = j & 255;
    int srow;
    if (R < 2048) {
      int h = R >> 7, c = R & 127, jj = c >> 4, l = c & 15;
      srow = h * 64 + (jj >> 1) * 16 + l;
      src = (jj & 1) ? wk : wq;
    } else if (R < 3072) { src = wv; srow = R - 2048; }
    else                 { src = wo; srow = R - 3072; }
    dst = Wb; soff = srow * 256 + col4; doff = R * 256 + col4;
  }
  float4 v = ((const float4*)src)[soff];
  uint2 o; o.x = pk2(v.x, v.y); o.y = pk2(v.z, v.w);
  ((uint2*)dst)[doff] = o;
}

// ---- QKV GEMM with fused score ---------------------------------------------
// C[M, 3072-virtual] = X[M,1024] * Wb[qk|v][.,1024]^T, bf16 operands.
// 128x128 tile, 4 waves (2x2 of 64x64), BK=32, mfma_f32_16x16x32_bf16.
// LDS double-buffered, staged by global_load_lds (1 barrier/tile; DMA for
// tile t+1 issued at top of iter t, drained by the compiler's vmcnt(0)
// before the barrier). XOR chunk swizzle: global chunk (l&3)^((l>>3)&3),
// fragment read chunk quad^((l16>>1)&3) -> conflict-free ds_read_b128.
// bn<16: head-tile -> score epilogue (writes only S). bn>=16: v-tile -> Vb.
__global__ __launch_bounds__(256, 4) void gemm_qkv_kernel(const u16* __restrict__ A,
                                                          const u16* __restrict__ B,
                                                          u16* __restrict__ Vb,
                                                          float* __restrict__ S) {
  constexpr int K = D_MODEL;
  __shared__ u16 As[2 * BUF];
  __shared__ u16 Bs[2 * BUF];
  const int tid  = threadIdx.x;
  const int lane = tid & 63;
  const int wave = tid >> 6;
  const int wm = (wave >> 1) * 64;
  const int wn = (wave & 1) * 64;
  const int bm = blockIdx.y * 128;
  const int bn = blockIdx.x;
  const int quad = lane >> 4;
  const int l16  = lane & 15;
  const int rchunk = quad ^ ((l16 >> 1) & 3);  // fragment read chunk

  // DMA staging: each wave stages 16 rows per cp16; lane -> row wave*16+(l>>2),
  // LDS chunk l&3 (dest = base + lane*16), global chunk (l&3)^((row>>1)&3).
  const int srow = lane >> 2;
  const int gch  = (lane & 3) ^ ((lane >> 3) & 3);
  const u16* Ag0 = A + (size_t)(bm + wave * 16 + srow) * K + gch * 8;
  const u16* Ag1 = Ag0 + (size_t)64 * K;
  const u16* Bg0 = B + (size_t)(bn * 128 + wave * 16 + srow) * K + gch * 8;
  const u16* Bg1 = Bg0 + (size_t)64 * K;
  u16* Al = As + wave * 16 * 32 + lane * 8;  // + parity*BUF at runtime
  u16* Bl = Bs + wave * 16 * 32 + lane * 8;

  f32x4 acc[4][4];
  #pragma unroll
  for (int i = 0; i < 4; ++i)
    #pragma unroll
    for (int j = 0; j < 4; ++j) acc[i][j] = (f32x4){0.f, 0.f, 0.f, 0.f};

  // prologue: DMA tile 0 -> buf0
  cp16(Ag0, Al);           cp16(Ag1, Al + 64 * 32);
  cp16(Bg0, Bl);           cp16(Bg1, Bl + 64 * 32);
  __syncthreads();

  #pragma unroll 2
  for (int t = 0; t < NT; ++t) {
    const int p = t & 1;
    const u16* Ar = As + p * BUF;
    const u16* Br = Bs + p * BUF;
    bf16x8 af[4], bfr[4];
    #pragma unroll
    for (int i = 0; i < 4; ++i)
      af[i] = *(const bf16x8*)(Ar + (wm + i * 16 + l16) * 32 + rchunk * 8);
    #pragma unroll
    for (int j = 0; j < 4; ++j)
      bfr[j] = *(const bf16x8*)(Br + (wn + j * 16 + l16) * 32 + rchunk * 8);
    if (t + 1 < NT) {  // DMA tile t+1 into the other buffer (drained at barrier)
      const int o = (t + 1) * 32;
      const int q = (p ^ 1) * BUF;
      cp16(Ag0 + o, Al + q);           cp16(Ag1 + o, Al + q + 64 * 32);
      cp16(Bg0 + o, Bl + q);           cp16(Bg1 + o, Bl + q + 64 * 32);
    }
    #pragma unroll
    for (int i = 0; i < 4; ++i)
      #pragma unroll
      for (int j = 0; j < 4; ++j)
        acc[i][j] = __builtin_amdgcn_mfma_f32_16x16x32_bf16(af[i], bfr[j], acc[i][j], 0, 0, 0);
    __syncthreads();
  }

  if (bn < N_HEADS) {
    // score epilogue: cols jj*16+l <-> (jj odd ? k : q)[d=(jj>>1)*16+l].
    // acc[i][j] (j even) pairs with acc[i][j+1]: q_d * k_d, same lane/row.
    float part[4][4];
    #pragma unroll
    for (int i = 0; i < 4; ++i)
      #pragma unroll
      for (int e = 0; e < 4; ++e)
        part[i][e] = acc[i][0][e] * acc[i][1][e] + acc[i][2][e] * acc[i][3][e];
    #pragma unroll
    for (int m = 1; m <= 8; m <<= 1)
      #pragma unroll
      for (int i = 0; i < 4; ++i)
        #pragma unroll
        for (int e = 0; e < 4; ++e)
          part[i][e] += __shfl_xor(part[i][e], m);  // reduce over l16
    __syncthreads();
    float* Sp = (float*)As;  // [128][2]
    if (l16 == 0) {
      #pragma unroll
      for (int i = 0; i < 4; ++i)
        #pragma unroll
        for (int e = 0; e < 4; ++e)
          Sp[(wm + i * 16 + quad * 4 + e) * 2 + (wave & 1)] = part[i][e];
    }
    __syncthreads();
    if (tid < 128) {
      float s = (Sp[tid * 2] + Sp[tid * 2 + 1]) * 0.125f;  // 1/sqrt(64)
      S[(size_t)(bm + tid) * N_HEADS + bn] = 1.f / (1.f + __expf(-s));
    }
  } else {
    const int cb = (bn - N_HEADS) * 128;
    #pragma unroll
    for (int i = 0; i < 4; ++i)
      #pragma unroll
      for (int j = 0; j < 4; ++j)
        #pragma unroll
        for (int e = 0; e < 4; ++e) {
          int row = bm + wm + i * 16 + quad * 4 + e;
          int col = cb + wn + j * 16 + l16;
          Vb[(size_t)row * D_MODEL + col] = f2bf(acc[i][j][e]);
        }
  }
}

// ---- out GEMM: out[M,1024] = (S(row,head)*V)[M,1024] * Wo[1024,1024]^T -----
// A = Vb bf16, reg-staged with fused S-scale (head = tile>>1), dbuf;
// B = Wo bf16, DMA-staged, dbuf. One barrier per tile.
__global__ __launch_bounds__(256, 4) void gemm_out_kernel(const u16* __restrict__ A,
                                                          const u16* __restrict__ B,
                                                          const float* __restrict__ S,
                                                          float* __restrict__ C) {
  constexpr int K = D_MODEL, N = D_MODEL;
  __shared__ u16 As[2 * BUF];
  __shared__ u16 Bs[2 * BUF];
  const int tid  = threadIdx.x;
  const int lane = tid & 63;
  const int wave = tid >> 6;
  const int wm = (wave >> 1) * 64;
  const int wn = (wave & 1) * 64;
  const int bm = blockIdx.y * 128;
  const int bn = blockIdx.x * 128;
  const int quad = lane >> 4;
  const int l16  = lane & 15;
  const int rchunk = quad ^ ((l16 >> 1) & 3);

  // A: register staging (scale must touch each element exactly once)
  const int lr = tid >> 2;
  const int lch = tid & 3;
  const int wch = lch ^ ((lr >> 1) & 3);
  const u16* Ap0 = A + (size_t)(bm + lr) * K + lch * 8;
  const u16* Ap1 = Ap0 + (size_t)64 * K;
  u16* Aw0 = As + lr * 32 + wch * 8;
  u16* Aw1 = Aw0 + 64 * 32;
  const float* Sp0 = S + (size_t)(bm + lr) * N_HEADS;
  const float* Sp1 = Sp0 + (size_t)64 * N_HEADS;

  // B: DMA staging
  const int srow = lane >> 2;
  const int gch  = (lane & 3) ^ ((lane >> 3) & 3);
  const u16* Bg0 = B + (size_t)(bn + wave * 16 + srow) * K + gch * 8;
  const u16* Bg1 = Bg0 + (size_t)64 * K;
  u16* Bl = Bs + wave * 16 * 32 + lane * 8;

  f32x4 acc[4][4];
  #pragma unroll
  for (int i = 0; i < 4; ++i)
    #pragma unroll
    for (int j = 0; j < 4; ++j) acc[i][j] = (f32x4){0.f, 0.f, 0.f, 0.f};

  // prologue: tile 0 -> buf0 (A scaled via regs, B via DMA); A-regs <- tile 1
  uint4 a0 = *(const uint4*)Ap0;
  uint4 a1 = *(const uint4*)Ap1;
  float rs0 = Sp0[0], rs1 = Sp1[0];
  cp16(Bg0, Bl);           cp16(Bg1, Bl + 64 * 32);
  {
    uint4 w0, w1;
    w0.x = scale2(a0.x, rs0); w0.y = scale2(a0.y, rs0);
    w0.z = scale2(a0.z, rs0); w0.w = scale2(a0.w, rs0);
    w1.x = scale2(a1.x, rs1); w1.y = scale2(a1.y, rs1);
    w1.z = scale2(a1.z, rs1); w1.w = scale2(a1.w, rs1);
    *(uint4*)Aw0 = w0; *(uint4*)Aw1 = w1;
  }
  a0 = *(const uint4*)(Ap0 + 32);
  a1 = *(const uint4*)(Ap1 + 32);
  // scales for tile 1: head = 1>>1 = 0 (rs unchanged)
  __syncthreads();

  #pragma unroll 2
  for (int t = 0; t < NT; ++t) {
    const int p = t & 1;
    const u16* Ar = As + p * BUF;
    const u16* Br = Bs + p * BUF;
    bf16x8 af[4], bfr[4];
    #pragma unroll
    for (int i = 0; i < 4; ++i)
      af[i] = *(const bf16x8*)(Ar + (wm + i * 16 + l16) * 32 + rchunk * 8);
    #pragma unroll
    for (int j = 0; j < 4; ++j)
      bfr[j] = *(const bf16x8*)(Br + (wn + j * 16 + l16) * 32 + rchunk * 8);
    if (t + 1 < NT) {
      const int q = (p ^ 1) * BUF;
      cp16(Bg0 + (t + 1) * 32, Bl + q);
      cp16(Bg1 + (t + 1) * 32, Bl + q + 64 * 32);
      uint4 w0, w1;
      w0.x = scale2(a0.x, rs0); w0.y = scale2(a0.y, rs0);
      w0.z = scale2(a0.z, rs0); w0.w = scale2(a0.w, rs0);
      w1.x = scale2(a1.x, rs1); w1.y = scale2(a1.y, rs1);
      w1.z = scale2(a1.z, rs1); w1.w = scale2(a1.w, rs1);
      *(uint4*)(Aw0 + q) = w0; *(uint4*)(Aw1 + q) = w1;
      if (t + 2 < NT) {  // prefetch A tile t+2 + its scale
        const int o = (t + 2) * 32;
        a0 = *(const uint4*)(Ap0 + o);
        a1 = *(const uint4*)(Ap1 + o);
        rs0 = Sp0[(t + 2) >> 1];
        rs1 = Sp1[(t + 2) >> 1];
      }
    }
    #pragma unroll
    for (int i = 0; i < 4; ++i)
      #pragma unroll
      for (int j = 0; j < 4; ++j)
        acc[i][j] = __builtin_amdgcn_mfma_f32_16x16x32_bf16(af[i], bfr[j], acc[i][j], 0, 0, 0);
    __syncthreads();
  }

  #pragma unroll
  for (int i = 0; i < 4; ++i)
    #pragma unroll
    for (int j = 0; j < 4; ++j)
      #pragma unroll
      for (int e = 0; e < 4; ++e) {
        int row = bm + wm + i * 16 + quad * 4 + e;
        int col = bn + wn + j * 16 + l16;
        C[(size_t)row * N + col] = acc[i][j][e];
      }
}

// ---- launch ----------------------------------------------------------------
extern "C" void kernel_launch(void* const* d_in, const int* in_sizes, int n_in,
                              void* d_out, int out_size, void* d_ws, size_t ws_size,
                              hipStream_t stream) {
  const float* hs = (const float*)d_in[0];
  const float* Wq = (const float*)d_in[3];
  const float* Wk = (const float*)d_in[4];
  const float* Wv = (const float*)d_in[5];
  const float* Wo = (const float*)d_in[6];
  // d_in[1,2,7,8,9] dead (fast-weight state identically zero).

  char* ws = (char*)d_ws;
  u16*  Xb = (u16*)ws;                     // [8192][1024] bf16 (16 MB)
  u16*  Wb = (u16*)(ws + (16u << 20));     // [4096][1024] bf16 qk|v|o (8 MB)
  u16*  Vb = (u16*)(ws + (24u << 20));     // [8192][1024] bf16 (16 MB)
  float* Sb = (float*)(ws + (40u << 20));  // [8192][16] f32 (512 KB)
  float* out = (float*)d_out;

  cast_kernel<<<12288, 256, 0, stream>>>(hs, Wq, Wk, Wv, Wo, Xb, Wb);
  gemm_qkv_kernel<<<dim3(24, 64), 256, 0, stream>>>(Xb, Wb, Vb, Sb);
  gemm_out_kernel<<<dim3(8, 64), 256, 0, stream>>>(
      Vb, Wb + (size_t)3072 * D_MODEL, Sb, out);
}

// Round 8
// 204.853 us; speedup vs baseline: 1.1703x; 1.0048x over previous
//
#include <hip/hip_runtime.h>
#include <hip/hip_bf16.h>
#include <stdint.h>

// CortexBlock — reference collapses (U,V start at 0; update is multiplicative
// in the state, so the fast-weight path is identically 0):
//   y[row,h,:] = sigmoid((q_h.k_h)/8) * v_h ;  out = y @ Wo^T
// Round 8 = best-of-measured: gemm_qkv from r6 (register-staged LDS double
// buffer, 68.5us: prefetch survives the barrier, unlike DMA which drains at
// the forced vmcnt(0)); gemm_out from r7 (A reg-staged with fused S-scale,
// B DMA-staged); cast kernel rewritten at 32B/thread with uint4 stores.
#define D_MODEL 1024
#define N_HEADS 16
#define D_HEAD  64
#define SEQ_T   2048
#define BATCH   4

typedef unsigned short u16;
typedef __bf16 bf16x8 __attribute__((ext_vector_type(8)));
typedef float  f32x4  __attribute__((ext_vector_type(4)));

#define NT 32          // K tiles (K=1024, BK=32)
#define BUF 4096       // u16 elements per LDS buffer (128*32)

// ---- helpers ---------------------------------------------------------------
__device__ __forceinline__ u16 f2bf(float x) {  // RNE f32->bf16
  unsigned u = __float_as_uint(x);
  u += 0x7fffu + ((u >> 16) & 1u);
  return (u16)(u >> 16);
}
__device__ __forceinline__ unsigned pk2(float a, float b) {
  return (unsigned)f2bf(a) | ((unsigned)f2bf(b) << 16);
}
__device__ __forceinline__ unsigned scale2(unsigned p, float s) {
  float lo = __uint_as_float(p << 16) * s;
  float hi = __uint_as_float(p & 0xffff0000u) * s;
  return pk2(lo, hi);
}
// async global->LDS, 16B per lane; LDS dest must be wave-uniform base+lane*16.
__device__ __forceinline__ void cp16(const u16* g, u16* l) {
  __builtin_amdgcn_global_load_lds(
      (const __attribute__((address_space(1))) unsigned int*)g,
      (__attribute__((address_space(3))) unsigned int*)l, 16, 0, 0);
}

// ---- fused cast fp32 -> bf16 with weight-row remap, 32B/thread -------------
// Wb rows: [0,2048): qk-interleaved: row h*128 + jj*16 + l  (jj=0..7) =
//   (jj odd ? Wk : Wq)[h*64 + (jj>>1)*16 + l];  [2048,3072): Wv; [3072,4096): Wo.
__global__ __launch_bounds__(256) void cast_kernel(const float* __restrict__ hs,
                                                   const float* __restrict__ wq,
                                                   const float* __restrict__ wk,
                                                   const float* __restrict__ wv,
                                                   const float* __restrict__ wo,
                                                   u16* __restrict__ Xb,
                                                   u16* __restrict__ Wb) {
  int g = blockIdx.x * 256 + threadIdx.x;  // 8-float groups; 1.5M total
  const float4* src; uint4* dst;
  if (g < (1 << 20)) {                     // X: 1M groups
    src = (const float4*)hs + 2 * (size_t)g;
    dst = (uint4*)Xb + g;
  } else {
    int j = g - (1 << 20);                 // W: 512K groups, 128 per row
    int R = j >> 7;                        // dest row (block-uniform branch mix ok)
    int col8 = j & 127;
    const float* s;
    int srow;
    if (R < 2048) {
      int h = R >> 7, c = R & 127, jj = c >> 4, l = c & 15;
      srow = h * 64 + (jj >> 1) * 16 + l;
      s = (jj & 1) ? wk : wq;
    } else if (R < 3072) { s = wv; srow = R - 2048; }
    else                 { s = wo; srow = R - 3072; }
    src = (const float4*)s + (size_t)srow * 256 + col8 * 2;
    dst = (uint4*)Wb + (size_t)R * 128 + col8;
  }
  float4 lo = src[0], hi = src[1];
  uint4 o;
  o.x = pk2(lo.x, lo.y); o.y = pk2(lo.z, lo.w);
  o.z = pk2(hi.x, hi.y); o.w = pk2(hi.z, hi.w);
  *dst = o;
}

// ---- QKV GEMM with fused score (r6 structure: reg-staged dbuf) -------------
// C[M, 3072-virtual] = X[M,1024] * Wb[qk|v][.,1024]^T, bf16 operands.
// 128x128 tile, 4 waves (2x2 of 64x64), BK=32, mfma_f32_16x16x32_bf16.
// LDS double-buffered, 1 barrier/tile: compute buf p while staging tile t+1
// into buf p^1 from regs prefetched a full iteration earlier. XOR chunk
// swizzle (chunk ^= (row>>1)&3): conflict-free ds_write_b128/ds_read_b128.
// bn<16: head-tile -> score epilogue (writes only S). bn>=16: v-tile -> Vb.
__global__ __launch_bounds__(256, 4) void gemm_qkv_kernel(const u16* __restrict__ A,
                                                          const u16* __restrict__ B,
                                                          u16* __restrict__ Vb,
                                                          float* __restrict__ S) {
  constexpr int K = D_MODEL;
  __shared__ u16 As[2 * BUF];
  __shared__ u16 Bs[2 * BUF];
  const int tid  = threadIdx.x;
  const int lane = tid & 63;
  const int wave = tid >> 6;
  const int wm = (wave >> 1) * 64;
  const int wn = (wave & 1) * 64;
  const int bm = blockIdx.y * 128;
  const int bn = blockIdx.x;
  const int quad = lane >> 4;
  const int l16  = lane & 15;
  const int rchunk = quad ^ ((l16 >> 1) & 3);  // fragment read chunk

  const int lr = tid >> 2;
  const int lch = tid & 3;
  const int wch = lch ^ ((lr >> 1) & 3);
  const u16* Ap0 = A + (size_t)(bm + lr) * K + lch * 8;
  const u16* Ap1 = Ap0 + (size_t)64 * K;
  const u16* Bp0 = B + (size_t)(bn * 128 + lr) * K + lch * 8;
  const u16* Bp1 = Bp0 + (size_t)64 * K;
  u16* Aw0 = As + lr * 32 + wch * 8;
  u16* Aw1 = Aw0 + 64 * 32;
  u16* Bw0 = Bs + lr * 32 + wch * 8;
  u16* Bw1 = Bw0 + 64 * 32;

  f32x4 acc[4][4];
  #pragma unroll
  for (int i = 0; i < 4; ++i)
    #pragma unroll
    for (int j = 0; j < 4; ++j) acc[i][j] = (f32x4){0.f, 0.f, 0.f, 0.f};

  // prologue: tile 0 -> buf0; regs <- tile 1
  uint4 a0 = *(const uint4*)Ap0;
  uint4 a1 = *(const uint4*)Ap1;
  uint4 b0 = *(const uint4*)Bp0;
  uint4 b1 = *(const uint4*)Bp1;
  *(uint4*)Aw0 = a0; *(uint4*)Aw1 = a1;
  *(uint4*)Bw0 = b0; *(uint4*)Bw1 = b1;
  a0 = *(const uint4*)(Ap0 + 32);
  a1 = *(const uint4*)(Ap1 + 32);
  b0 = *(const uint4*)(Bp0 + 32);
  b1 = *(const uint4*)(Bp1 + 32);
  __syncthreads();

  #pragma unroll 2
  for (int t = 0; t < NT; ++t) {
    const int p = t & 1;
    const u16* Ar = As + p * BUF;
    const u16* Br = Bs + p * BUF;
    bf16x8 af[4], bfr[4];
    #pragma unroll
    for (int i = 0; i < 4; ++i)
      af[i] = *(const bf16x8*)(Ar + (wm + i * 16 + l16) * 32 + rchunk * 8);
    #pragma unroll
    for (int j = 0; j < 4; ++j)
      bfr[j] = *(const bf16x8*)(Br + (wn + j * 16 + l16) * 32 + rchunk * 8);
    if (t + 1 < NT) {  // stage tile t+1 into other buffer
      const int q = (p ^ 1) * BUF;
      *(uint4*)(Aw0 + q) = a0; *(uint4*)(Aw1 + q) = a1;
      *(uint4*)(Bw0 + q) = b0; *(uint4*)(Bw1 + q) = b1;
      if (t + 2 < NT) {  // prefetch tile t+2 (consumed next iteration)
        const int o = (t + 2) * 32;
        a0 = *(const uint4*)(Ap0 + o);
        a1 = *(const uint4*)(Ap1 + o);
        b0 = *(const uint4*)(Bp0 + o);
        b1 = *(const uint4*)(Bp1 + o);
      }
    }
    #pragma unroll
    for (int i = 0; i < 4; ++i)
      #pragma unroll
      for (int j = 0; j < 4; ++j)
        acc[i][j] = __builtin_amdgcn_mfma_f32_16x16x32_bf16(af[i], bfr[j], acc[i][j], 0, 0, 0);
    __syncthreads();
  }

  if (bn < N_HEADS) {
    // score epilogue: cols jj*16+l <-> (jj odd ? k : q)[d=(jj>>1)*16+l].
    // acc[i][j] (j even) pairs with acc[i][j+1]: q_d * k_d, same lane/row.
    float part[4][4];
    #pragma unroll
    for (int i = 0; i < 4; ++i)
      #pragma unroll
      for (int e = 0; e < 4; ++e)
        part[i][e] = acc[i][0][e] * acc[i][1][e] + acc[i][2][e] * acc[i][3][e];
    #pragma unroll
    for (int m = 1; m <= 8; m <<= 1)
      #pragma unroll
      for (int i = 0; i < 4; ++i)
        #pragma unroll
        for (int e = 0; e < 4; ++e)
          part[i][e] += __shfl_xor(part[i][e], m);  // reduce over l16
    __syncthreads();
    float* Sp = (float*)As;  // [128][2]
    if (l16 == 0) {
      #pragma unroll
      for (int i = 0; i < 4; ++i)
        #pragma unroll
        for (int e = 0; e < 4; ++e)
          Sp[(wm + i * 16 + quad * 4 + e) * 2 + (wave & 1)] = part[i][e];
    }
    __syncthreads();
    if (tid < 128) {
      float s = (Sp[tid * 2] + Sp[tid * 2 + 1]) * 0.125f;  // 1/sqrt(64)
      S[(size_t)(bm + tid) * N_HEADS + bn] = 1.f / (1.f + __expf(-s));
    }
  } else {
    const int cb = (bn - N_HEADS) * 128;
    #pragma unroll
    for (int i = 0; i < 4; ++i)
      #pragma unroll
      for (int j = 0; j < 4; ++j)
        #pragma unroll
        for (int e = 0; e < 4; ++e) {
          int row = bm + wm + i * 16 + quad * 4 + e;
          int col = cb + wn + j * 16 + l16;
          Vb[(size_t)row * D_MODEL + col] = f2bf(acc[i][j][e]);
        }
  }
}

// ---- out GEMM (r7 structure): A reg-staged + S-scale, B DMA-staged ---------
// out[M,1024] = (S(row,head)*V)[M,1024] * Wo[1024,1024]^T.
__global__ __launch_bounds__(256, 4) void gemm_out_kernel(const u16* __restrict__ A,
                                                          const u16* __restrict__ B,
                                                          const float* __restrict__ S,
                                                          float* __restrict__ C) {
  constexpr int K = D_MODEL, N = D_MODEL;
  __shared__ u16 As[2 * BUF];
  __shared__ u16 Bs[2 * BUF];
  const int tid  = threadIdx.x;
  const int lane = tid & 63;
  const int wave = tid >> 6;
  const int wm = (wave >> 1) * 64;
  const int wn = (wave & 1) * 64;
  const int bm = blockIdx.y * 128;
  const int bn = blockIdx.x * 128;
  const int quad = lane >> 4;
  const int l16  = lane & 15;
  const int rchunk = quad ^ ((l16 >> 1) & 3);

  // A: register staging (scale must touch each element exactly once)
  const int lr = tid >> 2;
  const int lch = tid & 3;
  const int wch = lch ^ ((lr >> 1) & 3);
  const u16* Ap0 = A + (size_t)(bm + lr) * K + lch * 8;
  const u16* Ap1 = Ap0 + (size_t)64 * K;
  u16* Aw0 = As + lr * 32 + wch * 8;
  u16* Aw1 = Aw0 + 64 * 32;
  const float* Sp0 = S + (size_t)(bm + lr) * N_HEADS;
  const float* Sp1 = Sp0 + (size_t)64 * N_HEADS;

  // B: DMA staging
  const int srow = lane >> 2;
  const int gch  = (lane & 3) ^ ((lane >> 3) & 3);
  const u16* Bg0 = B + (size_t)(bn + wave * 16 + srow) * K + gch * 8;
  const u16* Bg1 = Bg0 + (size_t)64 * K;
  u16* Bl = Bs + wave * 16 * 32 + lane * 8;

  f32x4 acc[4][4];
  #pragma unroll
  for (int i = 0; i < 4; ++i)
    #pragma unroll
    for (int j = 0; j < 4; ++j) acc[i][j] = (f32x4){0.f, 0.f, 0.f, 0.f};

  // prologue: tile 0 -> buf0 (A scaled via regs, B via DMA); A-regs <- tile 1
  uint4 a0 = *(const uint4*)Ap0;
  uint4 a1 = *(const uint4*)Ap1;
  float rs0 = Sp0[0], rs1 = Sp1[0];
  cp16(Bg0, Bl);           cp16(Bg1, Bl + 64 * 32);
  {
    uint4 w0, w1;
    w0.x = scale2(a0.x, rs0); w0.y = scale2(a0.y, rs0);
    w0.z = scale2(a0.z, rs0); w0.w = scale2(a0.w, rs0);
    w1.x = scale2(a1.x, rs1); w1.y = scale2(a1.y, rs1);
    w1.z = scale2(a1.z, rs1); w1.w = scale2(a1.w, rs1);
    *(uint4*)Aw0 = w0; *(uint4*)Aw1 = w1;
  }
  a0 = *(const uint4*)(Ap0 + 32);
  a1 = *(const uint4*)(Ap1 + 32);
  // scales for tile 1: head = 1>>1 = 0 (rs unchanged)
  __syncthreads();

  #pragma unroll 2
  for (int t = 0; t < NT; ++t) {
    const int p = t & 1;
    const u16* Ar = As + p * BUF;
    const u16* Br = Bs + p * BUF;
    bf16x8 af[4], bfr[4];
    #pragma unroll
    for (int i = 0; i < 4; ++i)
      af[i] = *(const bf16x8*)(Ar + (wm + i * 16 + l16) * 32 + rchunk * 8);
    #pragma unroll
    for (int j = 0; j < 4; ++j)
      bfr[j] = *(const bf16x8*)(Br + (wn + j * 16 + l16) * 32 + rchunk * 8);
    if (t + 1 < NT) {
      const int q = (p ^ 1) * BUF;
      cp16(Bg0 + (t + 1) * 32, Bl + q);
      cp16(Bg1 + (t + 1) * 32, Bl + q + 64 * 32);
      uint4 w0, w1;
      w0.x = scale2(a0.x, rs0); w0.y = scale2(a0.y, rs0);
      w0.z = scale2(a0.z, rs0); w0.w = scale2(a0.w, rs0);
      w1.x = scale2(a1.x, rs1); w1.y = scale2(a1.y, rs1);
      w1.z = scale2(a1.z, rs1); w1.w = scale2(a1.w, rs1);
      *(uint4*)(Aw0 + q) = w0; *(uint4*)(Aw1 + q) = w1;
      if (t + 2 < NT) {  // prefetch A tile t+2 + its scale
        const int o = (t + 2) * 32;
        a0 = *(const uint4*)(Ap0 + o);
        a1 = *(const uint4*)(Ap1 + o);
        rs0 = Sp0[(t + 2) >> 1];
        rs1 = Sp1[(t + 2) >> 1];
      }
    }
    #pragma unroll
    for (int i = 0; i < 4; ++i)
      #pragma unroll
      for (int j = 0; j < 4; ++j)
        acc[i][j] = __builtin_amdgcn_mfma_f32_16x16x32_bf16(af[i], bfr[j], acc[i][j], 0, 0, 0);
    __syncthreads();
  }

  #pragma unroll
  for (int i = 0; i < 4; ++i)
    #pragma unroll
    for (int j = 0; j < 4; ++j)
      #pragma unroll
      for (int e = 0; e < 4; ++e) {
        int row = bm + wm + i * 16 + quad * 4 + e;
        int col = bn + wn + j * 16 + l16;
        C[(size_t)row * N + col] = acc[i][j][e];
      }
}

// ---- launch ----------------------------------------------------------------
extern "C" void kernel_launch(void* const* d_in, const int* in_sizes, int n_in,
                              void* d_out, int out_size, void* d_ws, size_t ws_size,
                              hipStream_t stream) {
  const float* hs = (const float*)d_in[0];
  const float* Wq = (const float*)d_in[3];
  const float* Wk = (const float*)d_in[4];
  const float* Wv = (const float*)d_in[5];
  const float* Wo = (const float*)d_in[6];
  // d_in[1,2,7,8,9] dead (fast-weight state identically zero).

  char* ws = (char*)d_ws;
  u16*  Xb = (u16*)ws;                     // [8192][1024] bf16 (16 MB)
  u16*  Wb = (u16*)(ws + (16u << 20));     // [4096][1024] bf16 qk|v|o (8 MB)
  u16*  Vb = (u16*)(ws + (24u << 20));     // [8192][1024] bf16 (16 MB)
  float* Sb = (float*)(ws + (40u << 20));  // [8192][16] f32 (512 KB)
  float* out = (float*)d_out;

  cast_kernel<<<6144, 256, 0, stream>>>(hs, Wq, Wk, Wv, Wo, Xb, Wb);
  gemm_qkv_kernel<<<dim3(24, 64), 256, 0, stream>>>(Xb, Wb, Vb, Sb);
  gemm_out_kernel<<<dim3(8, 64), 256, 0, stream>>>(
      Vb, Wb + (size_t)3072 * D_MODEL, Sb, out);
}